// Round 7
// baseline (117.702 us; speedup 1.0000x reference)
//
#include <hip/hip_runtime.h>
#include <math.h>

#define BLK  256
#define DD   128
#define NN   15
#define NL   16
#define OC   16
#define XH_STR  136   // x_hi row stride (bf16): 128 + 8 pad -> 2-way banks on frag reads
#define WN_STR  136   // Wn B-layout row stride (bf16)
#define XLO_STR 40    // x_lo chunk row stride (bf16): 32 + 8 pad
#define WSTR    40    // phase-3 Wl row stride (bf16)
#define NLSTR   17    // node-logit exchange stride (f32)
#define MAXT 32
#define TPW  8
#define GAPTHR 1e-3f

typedef __attribute__((ext_vector_type(8))) short short8v;
typedef __attribute__((ext_vector_type(4))) float f32x4;

__device__ inline unsigned bf16_rne(float f) {
    unsigned u = __float_as_uint(f);
    return (u + 0x7FFFu + ((u >> 16) & 1u)) >> 16;
}
__device__ inline unsigned pack_bf16(float a, float b) {   // low16 = a
    return bf16_rne(a) | (bf16_rne(b) << 16);
}
__device__ inline unsigned cvt_pk_bf16(float a, float b) { // low16 = a (HW RNE pack)
    unsigned r;
    asm volatile("v_cvt_pk_bf16_f32 %0, %1, %2" : "=v"(r) : "v"(a), "v"(b));
    return r;
}

__global__ __launch_bounds__(BLK, 1)
void dts_fused7(const float* __restrict__ x, const float* __restrict__ Wn,
                const float* __restrict__ bn, const float* __restrict__ Wl,
                const float* __restrict__ bl, float* __restrict__ out, int B)
{
    __shared__ __align__(16) unsigned short sXhi[BLK * XH_STR];   // 69632 B, persistent
    __shared__ __align__(16) char sUnion[20480];                  // x_lo chunk / sNL / sWT
    __shared__ __align__(16) unsigned short sWnHi[NL * WN_STR];   // 4352 B
    __shared__ __align__(16) unsigned short sWnLo[NL * WN_STR];   // 4352 B
    __shared__ float sBn[NN];
    __shared__ __align__(16) float sBl[NL * OC];
    __shared__ int sPerm[BLK];
    __shared__ int sBins[NL];
    __shared__ int sStarts[NL];
    __shared__ int sTleaf[MAXT];
    __shared__ int sTm0[MAXT];
    __shared__ int sTend[MAXT];
    __shared__ int sNT;

    unsigned short* sXlo = (unsigned short*)sUnion;   // [256][40] bf16 = 20480 B
    float*          sNL  = (float*)sUnion;            // [256][17] f32  = 17408 B
    unsigned short* sWT  = (unsigned short*)sUnion;   // [16][16][40] bf16 = 20480 B

    const int t   = threadIdx.x;
    const int wv  = t >> 6;
    const int lo  = t & 15;
    const int grp = (t >> 4) & 3;
    const int rowBase = blockIdx.x * BLK;
    const int row  = rowBase + t;
    const int rowL = (row < B) ? row : 0;
    const float4* xr = reinterpret_cast<const float4*>(x + (size_t)rowL * DD);

    // ---- stage Wn split (B-frag layout [node][k]), bn, bl ----
    for (int i = t; i < NL * DD; i += BLK) {
        int n = i >> 7, k = i & 127;
        float v = (n < NN) ? Wn[k * NN + n] : 0.f;    // Wn is [D][NN]; col 15 zero
        unsigned hb = bf16_rne(v);
        float hf = __uint_as_float(hb << 16);
        sWnHi[n * WN_STR + k] = (unsigned short)hb;
        sWnLo[n * WN_STR + k] = (unsigned short)bf16_rne(v - hf);
    }
    if (t < NN) sBn[t] = bn[t];
    for (int i = t; i < NL * OC; i += BLK) sBl[i] = bl[i];
    if (t < NL) sBins[t] = 0;

    // ---- phase 1: node logits via split-bf16 MFMA (3 terms) ----
    const int tb = wv * 4;                 // this wave's 4 row-tiles: tb..tb+3
    f32x4 accn[4];
    #pragma unroll
    for (int i = 0; i < 4; ++i) accn[i] = (f32x4){0.f, 0.f, 0.f, 0.f};

    #pragma unroll 1
    for (int c = 0; c < 4; ++c) {
        // load own x chunk (32 floats)
        float4 xv0 = xr[c*8+0], xv1 = xr[c*8+1], xv2 = xr[c*8+2], xv3 = xr[c*8+3];
        float4 xv4 = xr[c*8+4], xv5 = xr[c*8+5], xv6 = xr[c*8+6], xv7 = xr[c*8+7];

        __syncthreads();   // prev chunk's sXlo readers done (c=0: staging done)

        // convert hi/lo and stage: hi -> persistent column block, lo -> chunk buffer
        {
            unsigned hu[16], lu[16];
            #define CVT(q, vv) { \
                unsigned h0 = cvt_pk_bf16(vv.x, vv.y); \
                unsigned h1 = cvt_pk_bf16(vv.z, vv.w); \
                float a_ = vv.x - __uint_as_float(h0 << 16); \
                float b_ = vv.y - __uint_as_float(h0 & 0xFFFF0000u); \
                float c_ = vv.z - __uint_as_float(h1 << 16); \
                float d_ = vv.w - __uint_as_float(h1 & 0xFFFF0000u); \
                hu[(q)*2] = h0; hu[(q)*2+1] = h1; \
                lu[(q)*2] = cvt_pk_bf16(a_, b_); lu[(q)*2+1] = cvt_pk_bf16(c_, d_); }
            CVT(0, xv0) CVT(1, xv1) CVT(2, xv2) CVT(3, xv3)
            CVT(4, xv4) CVT(5, xv5) CVT(6, xv6) CVT(7, xv7)
            #undef CVT
            uint4* hd = (uint4*)&sXhi[t * XH_STR + c * 32];
            hd[0] = make_uint4(hu[0], hu[1], hu[2], hu[3]);
            hd[1] = make_uint4(hu[4], hu[5], hu[6], hu[7]);
            hd[2] = make_uint4(hu[8], hu[9], hu[10], hu[11]);
            hd[3] = make_uint4(hu[12], hu[13], hu[14], hu[15]);
            uint4* ld = (uint4*)&sXlo[t * XLO_STR];
            ld[0] = make_uint4(lu[0], lu[1], lu[2], lu[3]);
            ld[1] = make_uint4(lu[4], lu[5], lu[6], lu[7]);
            ld[2] = make_uint4(lu[8], lu[9], lu[10], lu[11]);
            ld[3] = make_uint4(lu[12], lu[13], lu[14], lu[15]);
        }
        __syncthreads();   // chunk visible

        const short8v bh = *(const short8v*)&sWnHi[lo * WN_STR + c * 32 + grp * 8];
        const short8v blo = *(const short8v*)&sWnLo[lo * WN_STR + c * 32 + grp * 8];
        #pragma unroll
        for (int i = 0; i < 4; ++i) {
            const int r0 = (tb + i) * 16 + lo;
            const short8v ah = *(const short8v*)&sXhi[r0 * XH_STR + c * 32 + grp * 8];
            const short8v al = *(const short8v*)&sXlo[r0 * XLO_STR + grp * 8];
            accn[i] = __builtin_amdgcn_mfma_f32_16x16x32_bf16(ah, bh, accn[i], 0, 0, 0);
            accn[i] = __builtin_amdgcn_mfma_f32_16x16x32_bf16(al, bh, accn[i], 0, 0, 0);
            accn[i] = __builtin_amdgcn_mfma_f32_16x16x32_bf16(ah, blo, accn[i], 0, 0, 0);
        }
    }

    // ---- exchange node logits: D layout col=lane&15(node), row=grp*4+j ----
    __syncthreads();   // last chunk's sXlo readers done; region becomes sNL
    #pragma unroll
    for (int i = 0; i < 4; ++i) {
        const int rb = (tb + i) * 16 + grp * 4;
        #pragma unroll
        for (int j = 0; j < 4; ++j) sNL[(rb + j) * NLSTR + lo] = accn[i][j];
    }
    __syncthreads();

    float nl[NN];
    #pragma unroll
    for (int n = 0; n < NN; ++n) nl[n] = sNL[t * NLSTR + n] + sBn[n];

    // ---- tree expand + top-2 argmax ----
    float L2a[4], L3a[8], L4a[16];
    #define EXPAND(src) { \
        float p = src[0], m = -src[0]; \
        L2a[0] = p + src[1]; L2a[1] = p - src[1]; \
        L2a[2] = m + src[2]; L2a[3] = m - src[2]; \
        _Pragma("unroll") \
        for (int i = 0; i < 4; ++i) { L3a[2*i] = L2a[i] + src[3+i]; L3a[2*i+1] = L2a[i] - src[3+i]; } \
        _Pragma("unroll") \
        for (int i = 0; i < 8; ++i) { L4a[2*i] = L3a[i] + src[7+i]; L4a[2*i+1] = L3a[i] - src[7+i]; } }
    EXPAND(nl)
    int best = 0; float bv = L4a[0], sv = -1e30f;
    #pragma unroll
    for (int l = 1; l < NL; ++l) {
        if (L4a[l] > bv) { sv = bv; bv = L4a[l]; best = l; }
        else if (L4a[l] > sv) sv = L4a[l];
    }

    // ---- rare exact f32 recompute for near-ties (argmax safety) ----
    if (bv - sv < GAPTHR) {
        float e[NN];
        #pragma unroll
        for (int n = 0; n < NN; ++n) e[n] = 0.f;
        const float* xrow = x + (size_t)rowL * DD;
        for (int d = 0; d < DD; ++d) {
            const float xd = xrow[d];
            const float* wr = Wn + d * NN;
            #pragma unroll
            for (int n = 0; n < NN; ++n) e[n] = fmaf(xd, wr[n], e[n]);
        }
        #pragma unroll
        for (int n = 0; n < NN; ++n) e[n] += sBn[n];
        EXPAND(e)
        best = 0; bv = L4a[0];
        #pragma unroll
        for (int l = 1; l < NL; ++l) if (L4a[l] > bv) { bv = L4a[l]; best = l; }
    }
    #undef EXPAND

    // ---- counting sort by leaf + tile list ----
    int rank = atomicAdd(&sBins[best], 1);
    __syncthreads();
    if (t == 0) {
        int s = 0, nt = 0;
        #pragma unroll
        for (int l = 0; l < NL; ++l) {
            sStarts[l] = s;
            int cn = sBins[l];
            for (int m0 = s; m0 < s + cn; m0 += 16) {
                sTleaf[nt] = l; sTm0[nt] = m0; sTend[nt] = s + cn; ++nt;
            }
            s += cn;
        }
        sNT = nt;
    }
    __syncthreads();
    const int slot = sStarts[best] + rank;
    sPerm[slot] = t;
    __syncthreads();
    const int nT = sNT;

    // ---- per-wave tile registers ----
    int tleaf[TPW], tm0[TPW], tend[TPW], arow[TPW], boff[TPW];
    #pragma unroll
    for (int i = 0; i < TPW; ++i) {
        int tid = wv + i * 4;
        bool v = tid < nT;
        tleaf[i] = v ? sTleaf[tid] : 0;
        tm0[i]   = v ? sTm0[tid]   : 0;
        tend[i]  = v ? sTend[tid]  : 0;
        arow[i]  = sPerm[tm0[i] + lo] * XH_STR;          // permuted row base (bf16 units)
        boff[i]  = tleaf[i] * (OC * WSTR) + lo * WSTR + grp * 8;
    }
    f32x4 accm[TPW];
    #pragma unroll
    for (int i = 0; i < TPW; ++i) accm[i] = (f32x4){0.f, 0.f, 0.f, 0.f};

    // Wl staging geometry: thread stages leaf t>>4, k-pair kk=t&15
    const int kk = t & 15;
    const int wleaf = t >> 4;
    unsigned short* wdst = &sWT[wleaf * (OC * WSTR) + kk * 2];

    // ---- phase 3: 4 k-chunks, MFMA; A-frags from persistent sXhi (permuted rows) ----
    #pragma unroll 1
    for (int c = 0; c < 4; ++c) {
        const float* gp = Wl + (size_t)wleaf * (DD * OC) + (size_t)(c * 32 + kk * 2) * OC;
        const float4 wa0 = *(const float4*)(gp);      const float4 wa1 = *(const float4*)(gp + 4);
        const float4 wa2 = *(const float4*)(gp + 8);  const float4 wa3 = *(const float4*)(gp + 12);
        const float4 wb0 = *(const float4*)(gp + 16); const float4 wb1 = *(const float4*)(gp + 20);
        const float4 wb2 = *(const float4*)(gp + 24); const float4 wb3 = *(const float4*)(gp + 28);

        __syncthreads();   // prev chunk's sWT readers done (c=0: sNL readers done)
        {
            *(unsigned*)&wdst[ 0*WSTR] = pack_bf16(wa0.x, wb0.x);
            *(unsigned*)&wdst[ 1*WSTR] = pack_bf16(wa0.y, wb0.y);
            *(unsigned*)&wdst[ 2*WSTR] = pack_bf16(wa0.z, wb0.z);
            *(unsigned*)&wdst[ 3*WSTR] = pack_bf16(wa0.w, wb0.w);
            *(unsigned*)&wdst[ 4*WSTR] = pack_bf16(wa1.x, wb1.x);
            *(unsigned*)&wdst[ 5*WSTR] = pack_bf16(wa1.y, wb1.y);
            *(unsigned*)&wdst[ 6*WSTR] = pack_bf16(wa1.z, wb1.z);
            *(unsigned*)&wdst[ 7*WSTR] = pack_bf16(wa1.w, wb1.w);
            *(unsigned*)&wdst[ 8*WSTR] = pack_bf16(wa2.x, wb2.x);
            *(unsigned*)&wdst[ 9*WSTR] = pack_bf16(wa2.y, wb2.y);
            *(unsigned*)&wdst[10*WSTR] = pack_bf16(wa2.z, wb2.z);
            *(unsigned*)&wdst[11*WSTR] = pack_bf16(wa2.w, wb2.w);
            *(unsigned*)&wdst[12*WSTR] = pack_bf16(wa3.x, wb3.x);
            *(unsigned*)&wdst[13*WSTR] = pack_bf16(wa3.y, wb3.y);
            *(unsigned*)&wdst[14*WSTR] = pack_bf16(wa3.z, wb3.z);
            *(unsigned*)&wdst[15*WSTR] = pack_bf16(wa3.w, wb3.w);
        }
        __syncthreads();

        #pragma unroll
        for (int i = 0; i < TPW; ++i) {
            if (wv + i * 4 < nT) {
                const short8v af = *(const short8v*)&sXhi[arow[i] + c * 32 + grp * 8];
                const short8v bf = *(const short8v*)&sWT[boff[i]];
                accm[i] = __builtin_amdgcn_mfma_f32_16x16x32_bf16(af, bf, accm[i], 0, 0, 0);
            }
        }
    }

    // ---- epilogue: bias + squash + predicated store (D: col=lane&15, row=grp*4+j) ----
    #pragma unroll
    for (int i = 0; i < TPW; ++i) {
        if (wv + i * 4 < nT) {
            const float bias = sBl[tleaf[i] * OC + lo];
            #pragma unroll
            for (int j = 0; j < 4; ++j) {
                const int sl = tm0[i] + grp * 4 + j;
                if (sl < tend[i]) {
                    const int r = sPerm[sl];
                    const size_t grow = (size_t)rowBase + r;
                    const float v = accm[i][j] + bias;
                    if (lo < 8) {
                        out[grow * 8 + lo] = v;
                    } else {
                        out[(size_t)B * 8 + grow * 8 + (lo - 8)] =
                            -1.5f + 3.5f * (1.f - 2.f / (__expf(2.f * v) + 1.f));
                    }
                }
            }
        }
    }
}

extern "C" void kernel_launch(void* const* d_in, const int* in_sizes, int n_in,
                              void* d_out, int out_size, void* d_ws, size_t ws_size,
                              hipStream_t stream)
{
    const float* x  = (const float*)d_in[0];
    const float* Wn = (const float*)d_in[1];
    const float* bn = (const float*)d_in[2];
    const float* Wl = (const float*)d_in[3];
    const float* bl = (const float*)d_in[4];
    float* out = (float*)d_out;

    const int B = in_sizes[0] / DD;              // 262144
    const int blocks = (B + BLK - 1) / BLK;      // 1024

    hipLaunchKernelGGL(dts_fused7, dim3(blocks), dim3(BLK), 0, stream,
                       x, Wn, bn, Wl, bl, out, B);
}

// Round 8
// 90.599 us; speedup vs baseline: 1.2992x; 1.2992x over previous
//
#include <hip/hip_runtime.h>
#include <math.h>

#define BLK  256
#define DD   128
#define NN   15
#define NL   16
#define OC   16
#define WN_STR 136    // Wn hi/lo row stride (bf16)
#define XSTR   40     // x chunk-buffer row stride (bf16): 32 data + 8 pad (80B, 16B-aligned)
#define LSTR   656    // sWT per-leaf stride (bf16): 16*40 + 16 pad -> bank shift 8/leaf
#define WROW   40     // sWT per-out-channel stride (bf16)
#define NLSTR  20     // node-logit exchange stride (f32, 80B rows)
#define MAXT 32
#define TPW  8
#define GAPTHR 1e-3f

typedef __attribute__((ext_vector_type(8))) short short8v;
typedef __attribute__((ext_vector_type(4))) float f32x4;

__device__ inline unsigned bf16_rne(float f) {
    unsigned u = __float_as_uint(f);
    return (u + 0x7FFFu + ((u >> 16) & 1u)) >> 16;
}
__device__ inline unsigned cvt_pk_bf16(float a, float b) {  // low16 = a (HW RNE)
    unsigned r;
    asm volatile("v_cvt_pk_bf16_f32 %0, %1, %2" : "=v"(r) : "v"(a), "v"(b));
    return r;
}

__global__ __launch_bounds__(BLK, 3)
void dts_fused8(const float* __restrict__ x, const float* __restrict__ Wn,
                const float* __restrict__ bn, const float* __restrict__ Wl,
                const float* __restrict__ bl, float* __restrict__ out, int B)
{
    // union region: phase1 = xhi[256][40] + xlo[256][40] (40960B)
    //               exchange = sNL f32[256][20] (20480B)
    //               phase3 = sWT bf16[16][656] (20992B) + xsrt bf16[256][40] (20480B)
    __shared__ __align__(16) char uA[41472];
    __shared__ __align__(16) unsigned short sWnHi[NL * WN_STR];   // 4352B
    __shared__ __align__(16) unsigned short sWnLo[NL * WN_STR];   // 4352B
    __shared__ float sBn[NN];
    __shared__ __align__(16) float sBl[NL * OC];
    __shared__ int sPerm[BLK];
    __shared__ int sBins[NL];
    __shared__ int sStarts[NL];
    __shared__ int sTleaf[MAXT];
    __shared__ int sTm0[MAXT];
    __shared__ int sTend[MAXT];
    __shared__ int sNT;

    unsigned short* xhi  = (unsigned short*)uA;             // [256][40]
    unsigned short* xlo  = (unsigned short*)(uA + 20480);   // [256][40]
    float*          sNL  = (float*)uA;                      // [256][20]
    unsigned short* sWT  = (unsigned short*)uA;             // [16][656]
    unsigned short* xsrt = (unsigned short*)(uA + 20992);   // [256][40]

    const int t    = threadIdx.x;
    const int wv   = t >> 6;
    const int lo16 = t & 15;
    const int grp  = (t >> 4) & 3;
    const int rowBase = blockIdx.x * BLK;
    const int row  = rowBase + t;
    const int rowL = (row < B) ? row : 0;
    const float4* xr = reinterpret_cast<const float4*>(x + (size_t)rowL * DD);

    // ---- stage Wn split hi/lo in B-frag layout [node][k], bn, bl ----
    for (int i = t; i < NL * DD; i += BLK) {
        int n = i >> 7, k = i & 127;
        float v = (n < NN) ? Wn[k * NN + n] : 0.f;    // Wn is [D][NN]; col 15 zero
        unsigned hb = bf16_rne(v);
        float hf = __uint_as_float(hb << 16);
        sWnHi[n * WN_STR + k] = (unsigned short)hb;
        sWnLo[n * WN_STR + k] = (unsigned short)bf16_rne(v - hf);
    }
    if (t < NN) sBn[t] = bn[t];
    for (int i = t; i < NL * OC; i += BLK) sBl[i] = bl[i];
    if (t < NL) sBins[t] = 0;

    // ---- phase 1: node logits via split-bf16 MFMA, chunk-wise x exchange ----
    const int tb = wv * 4;
    f32x4 accn[4];
    #pragma unroll
    for (int i = 0; i < 4; ++i) accn[i] = (f32x4){0.f, 0.f, 0.f, 0.f};

    #pragma unroll 1
    for (int c = 0; c < 4; ++c) {
        const float4 xv0 = xr[c*8+0], xv1 = xr[c*8+1], xv2 = xr[c*8+2], xv3 = xr[c*8+3];
        const float4 xv4 = xr[c*8+4], xv5 = xr[c*8+5], xv6 = xr[c*8+6], xv7 = xr[c*8+7];

        __syncthreads();   // prev chunk's frag readers done (c=0: Wn staging done too)
        {
            unsigned hu[16], lu[16];
            #define CVT(q, vv) { \
                unsigned h0 = cvt_pk_bf16(vv.x, vv.y); \
                unsigned h1 = cvt_pk_bf16(vv.z, vv.w); \
                float a_ = vv.x - __uint_as_float(h0 << 16); \
                float b_ = vv.y - __uint_as_float(h0 & 0xFFFF0000u); \
                float c_ = vv.z - __uint_as_float(h1 << 16); \
                float d_ = vv.w - __uint_as_float(h1 & 0xFFFF0000u); \
                hu[(q)*2] = h0; hu[(q)*2+1] = h1; \
                lu[(q)*2] = cvt_pk_bf16(a_, b_); lu[(q)*2+1] = cvt_pk_bf16(c_, d_); }
            CVT(0, xv0) CVT(1, xv1) CVT(2, xv2) CVT(3, xv3)
            CVT(4, xv4) CVT(5, xv5) CVT(6, xv6) CVT(7, xv7)
            #undef CVT
            uint4* hd = (uint4*)&xhi[t * XSTR];
            hd[0] = make_uint4(hu[0], hu[1], hu[2], hu[3]);
            hd[1] = make_uint4(hu[4], hu[5], hu[6], hu[7]);
            hd[2] = make_uint4(hu[8], hu[9], hu[10], hu[11]);
            hd[3] = make_uint4(hu[12], hu[13], hu[14], hu[15]);
            uint4* ld = (uint4*)&xlo[t * XSTR];
            ld[0] = make_uint4(lu[0], lu[1], lu[2], lu[3]);
            ld[1] = make_uint4(lu[4], lu[5], lu[6], lu[7]);
            ld[2] = make_uint4(lu[8], lu[9], lu[10], lu[11]);
            ld[3] = make_uint4(lu[12], lu[13], lu[14], lu[15]);
        }
        __syncthreads();   // chunk visible

        const short8v bh = *(const short8v*)&sWnHi[lo16 * WN_STR + c * 32 + grp * 8];
        const short8v bw = *(const short8v*)&sWnLo[lo16 * WN_STR + c * 32 + grp * 8];
        #pragma unroll
        for (int i = 0; i < 4; ++i) {
            const int r0 = (tb + i) * 16 + lo16;
            const short8v ah = *(const short8v*)&xhi[r0 * XSTR + grp * 8];
            const short8v al = *(const short8v*)&xlo[r0 * XSTR + grp * 8];
            accn[i] = __builtin_amdgcn_mfma_f32_16x16x32_bf16(ah, bh, accn[i], 0, 0, 0);
            accn[i] = __builtin_amdgcn_mfma_f32_16x16x32_bf16(al, bh, accn[i], 0, 0, 0);
            accn[i] = __builtin_amdgcn_mfma_f32_16x16x32_bf16(ah, bw, accn[i], 0, 0, 0);
        }
    }

    // ---- exchange node logits (D: col=lane&15 -> node, row=grp*4+j) ----
    __syncthreads();   // last chunk frag reads done; region becomes sNL
    #pragma unroll
    for (int i = 0; i < 4; ++i) {
        const int rb = (tb + i) * 16 + grp * 4;
        #pragma unroll
        for (int j = 0; j < 4; ++j) sNL[(rb + j) * NLSTR + lo16] = accn[i][j];
    }
    __syncthreads();

    float nl[16];
    {
        const float4* np = (const float4*)&sNL[t * NLSTR];
        const float4 n0 = np[0], n1 = np[1], n2 = np[2], n3 = np[3];
        nl[0]=n0.x; nl[1]=n0.y; nl[2]=n0.z; nl[3]=n0.w;
        nl[4]=n1.x; nl[5]=n1.y; nl[6]=n1.z; nl[7]=n1.w;
        nl[8]=n2.x; nl[9]=n2.y; nl[10]=n2.z; nl[11]=n2.w;
        nl[12]=n3.x; nl[13]=n3.y; nl[14]=n3.z;
    }
    #pragma unroll
    for (int n = 0; n < NN; ++n) nl[n] += sBn[n];

    // ---- tree expand + top-2 argmax ----
    float L2a[4], L3a[8], L4a[16];
    #define EXPAND(src) { \
        float p = src[0], m = -src[0]; \
        L2a[0] = p + src[1]; L2a[1] = p - src[1]; \
        L2a[2] = m + src[2]; L2a[3] = m - src[2]; \
        _Pragma("unroll") \
        for (int i = 0; i < 4; ++i) { L3a[2*i] = L2a[i] + src[3+i]; L3a[2*i+1] = L2a[i] - src[3+i]; } \
        _Pragma("unroll") \
        for (int i = 0; i < 8; ++i) { L4a[2*i] = L3a[i] + src[7+i]; L4a[2*i+1] = L3a[i] - src[7+i]; } }
    EXPAND(nl)
    int best = 0; float bv = L4a[0], sv = -1e30f;
    #pragma unroll
    for (int l = 1; l < NL; ++l) {
        if (L4a[l] > bv) { sv = bv; bv = L4a[l]; best = l; }
        else if (L4a[l] > sv) sv = L4a[l];
    }

    // ---- rare exact f32 recompute for near-ties ----
    if (bv - sv < GAPTHR) {
        float e[NN];
        #pragma unroll
        for (int n = 0; n < NN; ++n) e[n] = 0.f;
        const float* xrow = x + (size_t)rowL * DD;
        for (int d = 0; d < DD; ++d) {
            const float xd = xrow[d];
            const float* wr = Wn + d * NN;
            #pragma unroll
            for (int n = 0; n < NN; ++n) e[n] = fmaf(xd, wr[n], e[n]);
        }
        #pragma unroll
        for (int n = 0; n < NN; ++n) e[n] += sBn[n];
        EXPAND(e)
        best = 0; bv = L4a[0];
        #pragma unroll
        for (int l = 1; l < NL; ++l) if (L4a[l] > bv) { bv = L4a[l]; best = l; }
    }
    #undef EXPAND

    // ---- counting sort by leaf + ragged 16-row tile list ----
    int rank = atomicAdd(&sBins[best], 1);
    __syncthreads();   // also: all sNL reads complete
    if (t == 0) {
        int s = 0, nt = 0;
        #pragma unroll
        for (int l = 0; l < NL; ++l) {
            sStarts[l] = s;
            int cn = sBins[l];
            for (int m0 = s; m0 < s + cn; m0 += 16) {
                sTleaf[nt] = l; sTm0[nt] = m0; sTend[nt] = s + cn; ++nt;
            }
            s += cn;
        }
        sNT = nt;
    }
    __syncthreads();
    const int slot = sStarts[best] + rank;
    sPerm[slot] = t;
    __syncthreads();
    const int nT = sNT;

    int tleaf[TPW], tm0[TPW], tend[TPW];
    #pragma unroll
    for (int i = 0; i < TPW; ++i) {
        int tid = wv + i * 4;
        bool v = tid < nT;
        tleaf[i] = v ? sTleaf[tid] : 0;
        tm0[i]   = v ? sTm0[tid]   : 0;
        tend[i]  = v ? sTend[tid]  : 0;
    }
    f32x4 accm[TPW];
    #pragma unroll
    for (int i = 0; i < TPW; ++i) accm[i] = (f32x4){0.f, 0.f, 0.f, 0.f};

    // Wl staging geometry: thread stages leaf t>>4, k-pair kk=t&15
    const int kk = t & 15;
    const int wleaf = t >> 4;
    unsigned short* wdst = &sWT[wleaf * LSTR + kk * 2];
    unsigned short* xdst = &xsrt[slot * XSTR];

    // ---- phase 3: 4 k-chunks of 32; sorted-slot x + transposed Wl in LDS; MFMA ----
    #pragma unroll 1
    for (int c = 0; c < 4; ++c) {
        const float4 xv0 = xr[c*8+0], xv1 = xr[c*8+1], xv2 = xr[c*8+2], xv3 = xr[c*8+3];
        const float4 xv4 = xr[c*8+4], xv5 = xr[c*8+5], xv6 = xr[c*8+6], xv7 = xr[c*8+7];
        const float* gp = Wl + (size_t)wleaf * (DD * OC) + (size_t)(c * 32 + kk * 2) * OC;
        const float4 wa0 = *(const float4*)(gp);      const float4 wa1 = *(const float4*)(gp + 4);
        const float4 wa2 = *(const float4*)(gp + 8);  const float4 wa3 = *(const float4*)(gp + 12);
        const float4 wb0 = *(const float4*)(gp + 16); const float4 wb1 = *(const float4*)(gp + 20);
        const float4 wb2 = *(const float4*)(gp + 24); const float4 wb3 = *(const float4*)(gp + 28);

        __syncthreads();   // prev chunk frag readers done (c=0: sNL readers done)
        {
            uint4* xd = (uint4*)xdst;
            xd[0] = make_uint4(cvt_pk_bf16(xv0.x,xv0.y), cvt_pk_bf16(xv0.z,xv0.w),
                               cvt_pk_bf16(xv1.x,xv1.y), cvt_pk_bf16(xv1.z,xv1.w));
            xd[1] = make_uint4(cvt_pk_bf16(xv2.x,xv2.y), cvt_pk_bf16(xv2.z,xv2.w),
                               cvt_pk_bf16(xv3.x,xv3.y), cvt_pk_bf16(xv3.z,xv3.w));
            xd[2] = make_uint4(cvt_pk_bf16(xv4.x,xv4.y), cvt_pk_bf16(xv4.z,xv4.w),
                               cvt_pk_bf16(xv5.x,xv5.y), cvt_pk_bf16(xv5.z,xv5.w));
            xd[3] = make_uint4(cvt_pk_bf16(xv6.x,xv6.y), cvt_pk_bf16(xv6.z,xv6.w),
                               cvt_pk_bf16(xv7.x,xv7.y), cvt_pk_bf16(xv7.z,xv7.w));
            *(unsigned*)&wdst[ 0*WROW] = cvt_pk_bf16(wa0.x, wb0.x);
            *(unsigned*)&wdst[ 1*WROW] = cvt_pk_bf16(wa0.y, wb0.y);
            *(unsigned*)&wdst[ 2*WROW] = cvt_pk_bf16(wa0.z, wb0.z);
            *(unsigned*)&wdst[ 3*WROW] = cvt_pk_bf16(wa0.w, wb0.w);
            *(unsigned*)&wdst[ 4*WROW] = cvt_pk_bf16(wa1.x, wb1.x);
            *(unsigned*)&wdst[ 5*WROW] = cvt_pk_bf16(wa1.y, wb1.y);
            *(unsigned*)&wdst[ 6*WROW] = cvt_pk_bf16(wa1.z, wb1.z);
            *(unsigned*)&wdst[ 7*WROW] = cvt_pk_bf16(wa1.w, wb1.w);
            *(unsigned*)&wdst[ 8*WROW] = cvt_pk_bf16(wa2.x, wb2.x);
            *(unsigned*)&wdst[ 9*WROW] = cvt_pk_bf16(wa2.y, wb2.y);
            *(unsigned*)&wdst[10*WROW] = cvt_pk_bf16(wa2.z, wb2.z);
            *(unsigned*)&wdst[11*WROW] = cvt_pk_bf16(wa2.w, wb2.w);
            *(unsigned*)&wdst[12*WROW] = cvt_pk_bf16(wa3.x, wb3.x);
            *(unsigned*)&wdst[13*WROW] = cvt_pk_bf16(wa3.y, wb3.y);
            *(unsigned*)&wdst[14*WROW] = cvt_pk_bf16(wa3.z, wb3.z);
            *(unsigned*)&wdst[15*WROW] = cvt_pk_bf16(wa3.w, wb3.w);
        }
        __syncthreads();   // chunk visible

        #pragma unroll
        for (int i = 0; i < TPW; ++i) {
            if (wv + i * 4 < nT) {   // wave-uniform
                const short8v af = *(const short8v*)&xsrt[(tm0[i] + lo16) * XSTR + grp * 8];
                const short8v bf = *(const short8v*)&sWT[tleaf[i] * LSTR + lo16 * WROW + grp * 8];
                accm[i] = __builtin_amdgcn_mfma_f32_16x16x32_bf16(af, bf, accm[i], 0, 0, 0);
            }
        }
    }

    // ---- epilogue: bias + squash + predicated store (D: col=lane&15, row=grp*4+j) ----
    #pragma unroll
    for (int i = 0; i < TPW; ++i) {
        if (wv + i * 4 < nT) {
            const float bias = sBl[tleaf[i] * OC + lo16];
            #pragma unroll
            for (int j = 0; j < 4; ++j) {
                const int sl = tm0[i] + grp * 4 + j;
                if (sl < tend[i]) {
                    const int r = sPerm[sl];
                    const size_t grow = (size_t)rowBase + r;
                    const float v = accm[i][j] + bias;
                    if (lo16 < 8) {
                        out[grow * 8 + lo16] = v;
                    } else {
                        // log_std = -1.5 + 3.5*tanh(v); tanh = 1 - 2/(e^{2v}+1)
                        out[(size_t)B * 8 + grow * 8 + (lo16 - 8)] =
                            -1.5f + 3.5f * (1.f - 2.f / (__expf(2.f * v) + 1.f));
                    }
                }
            }
        }
    }
}

extern "C" void kernel_launch(void* const* d_in, const int* in_sizes, int n_in,
                              void* d_out, int out_size, void* d_ws, size_t ws_size,
                              hipStream_t stream)
{
    const float* x  = (const float*)d_in[0];
    const float* Wn = (const float*)d_in[1];
    const float* bn = (const float*)d_in[2];
    const float* Wl = (const float*)d_in[3];
    const float* bl = (const float*)d_in[4];
    float* out = (float*)d_out;

    const int B = in_sizes[0] / DD;              // 262144
    const int blocks = (B + BLK - 1) / BLK;      // 1024

    hipLaunchKernelGGL(dts_fused8, dim3(blocks), dim3(BLK), 0, stream,
                       x, Wn, bn, Wl, bl, out, B);
}

// Round 9
// 72.011 us; speedup vs baseline: 1.6345x; 1.2581x over previous
//
#include <hip/hip_runtime.h>
#include <math.h>

#define BLK  256
#define DD   128
#define NN   15
#define NL   16
#define OC   16
#define NLSTR 20     // node-logit patch row stride (f32): 80B, 16B-aligned, 8-way worst
#define MAXT 32
#define TPW  8
#define GAPTHR 1e-3f

typedef __attribute__((ext_vector_type(8))) short short8v;
typedef __attribute__((ext_vector_type(4))) float f32x4;
typedef union { unsigned u[4]; short8v s; } fragu;

__device__ inline unsigned cvt_pk_bf16(float a, float b) {  // low16 = a (HW RNE)
    unsigned r;
    asm volatile("v_cvt_pk_bf16_f32 %0, %1, %2" : "=v"(r) : "v"(a), "v"(b));
    return r;
}

// split 8 f32 into bf16 hi + bf16 residual fragments
__device__ inline void split8(const float v[8], short8v& hi, short8v& lo) {
    fragu H, L;
    #pragma unroll
    for (int p = 0; p < 4; ++p) {
        const float a = v[2*p], b = v[2*p+1];
        const unsigned h = cvt_pk_bf16(a, b);
        H.u[p] = h;
        const float ra = a - __uint_as_float(h << 16);
        const float rb = b - __uint_as_float(h & 0xFFFF0000u);
        L.u[p] = cvt_pk_bf16(ra, rb);
    }
    hi = H.s; lo = L.s;
}
__device__ inline short8v pack8hi(const float v[8]) {
    fragu H;
    #pragma unroll
    for (int p = 0; p < 4; ++p) H.u[p] = cvt_pk_bf16(v[2*p], v[2*p+1]);
    return H.s;
}

__global__ __launch_bounds__(BLK, 4)
void dts_fused9(const float* __restrict__ x, const float* __restrict__ Wn,
                const float* __restrict__ bn, const float* __restrict__ Wl,
                const float* __restrict__ bl, float* __restrict__ out, int B)
{
    __shared__ __align__(16) float sNLw[4][64 * NLSTR];   // 20480B: per-wave logit patch
    __shared__ float sBn[NN];
    __shared__ __align__(16) float sBl[NL * OC];
    __shared__ int sPerm[BLK + 16];   // +16 pad (ragged tile overread)
    __shared__ int sBins[NL];
    __shared__ int sStarts[NL];
    __shared__ int sTleaf[MAXT];
    __shared__ int sTm0[MAXT];
    __shared__ int sTend[MAXT];
    __shared__ int sNT;

    const int t    = threadIdx.x;
    const int wv   = t >> 6;
    const int lane = t & 63;
    const int lo16 = t & 15;
    const int grp  = (t >> 4) & 3;    // == (lane>>4) since 64 | wv*64
    const int rowBase = blockIdx.x * BLK;   // B == 262144 = grid*256 exactly

    if (t < NN) sBn[t] = bn[t];
    for (int i = t; i < NL * OC; i += BLK) sBl[i] = bl[i];
    if (t < NL) sBins[t] = 0;
    if (t < 16) sPerm[BLK + t] = 0;
    __syncthreads();                                   // barrier 1

    // ================= phase 1: node logits, per-wave MFMA from global =================
    const int waveRow0 = rowBase + wv * 64;
    f32x4 accn[4];
    #pragma unroll
    for (int i = 0; i < 4; ++i) accn[i] = (f32x4){0.f, 0.f, 0.f, 0.f};

    #pragma unroll 1
    for (int c = 0; c < 4; ++c) {
        // B-frag: Wn[k][node] hi/lo, node = lo16 (col 15 zeroed)
        float bvv[8];
        #pragma unroll
        for (int j = 0; j < 8; ++j) {
            const int k = c * 32 + grp * 8 + j;
            bvv[j] = (lo16 < NN) ? Wn[k * NN + lo16] : 0.f;
        }
        short8v bh, bw;
        split8(bvv, bh, bw);

        #pragma unroll
        for (int i = 0; i < 4; ++i) {
            const float* ap = x + (size_t)(waveRow0 + i * 16 + lo16) * DD + c * 32 + grp * 8;
            const float4 a0 = *(const float4*)ap;
            const float4 a1 = *(const float4*)(ap + 4);
            float av[8];
            av[0]=a0.x; av[1]=a0.y; av[2]=a0.z; av[3]=a0.w;
            av[4]=a1.x; av[5]=a1.y; av[6]=a1.z; av[7]=a1.w;
            short8v ah, al;
            split8(av, ah, al);
            accn[i] = __builtin_amdgcn_mfma_f32_16x16x32_bf16(ah, bh, accn[i], 0, 0, 0);
            accn[i] = __builtin_amdgcn_mfma_f32_16x16x32_bf16(al, bh, accn[i], 0, 0, 0);
            accn[i] = __builtin_amdgcn_mfma_f32_16x16x32_bf16(ah, bw, accn[i], 0, 0, 0);
        }
    }

    // ---- in-wave transpose through private patch (no block barrier) ----
    float* patch = &sNLw[wv][0];
    #pragma unroll
    for (int i = 0; i < 4; ++i)
        #pragma unroll
        for (int j = 0; j < 4; ++j)
            patch[(i * 16 + grp * 4 + j) * NLSTR + lo16] = accn[i][j];
    asm volatile("s_waitcnt lgkmcnt(0)" ::: "memory");   // in-wave write->read ordering
    __builtin_amdgcn_sched_barrier(0);

    float nl[16];
    {
        const float4* np = (const float4*)&patch[lane * NLSTR];
        const float4 n0 = np[0], n1 = np[1], n2 = np[2], n3 = np[3];
        nl[0]=n0.x; nl[1]=n0.y; nl[2]=n0.z;  nl[3]=n0.w;
        nl[4]=n1.x; nl[5]=n1.y; nl[6]=n1.z;  nl[7]=n1.w;
        nl[8]=n2.x; nl[9]=n2.y; nl[10]=n2.z; nl[11]=n2.w;
        nl[12]=n3.x; nl[13]=n3.y; nl[14]=n3.z;
    }
    #pragma unroll
    for (int n = 0; n < NN; ++n) nl[n] += sBn[n];

    // ---- tree expand + top-2 argmax ----
    float L2a[4], L3a[8], L4a[16];
    #define EXPAND(src) { \
        float p = src[0], m = -src[0]; \
        L2a[0] = p + src[1]; L2a[1] = p - src[1]; \
        L2a[2] = m + src[2]; L2a[3] = m - src[2]; \
        _Pragma("unroll") \
        for (int i = 0; i < 4; ++i) { L3a[2*i] = L2a[i] + src[3+i]; L3a[2*i+1] = L2a[i] - src[3+i]; } \
        _Pragma("unroll") \
        for (int i = 0; i < 8; ++i) { L4a[2*i] = L3a[i] + src[7+i]; L4a[2*i+1] = L3a[i] - src[7+i]; } }
    EXPAND(nl)
    int best = 0; float bv = L4a[0], sv = -1e30f;
    #pragma unroll
    for (int l = 1; l < NL; ++l) {
        if (L4a[l] > bv) { sv = bv; bv = L4a[l]; best = l; }
        else if (L4a[l] > sv) sv = L4a[l];
    }

    // rare exact f32 recompute for near-ties
    if (bv - sv < GAPTHR) {
        float e[NN];
        #pragma unroll
        for (int n = 0; n < NN; ++n) e[n] = 0.f;
        const float* xrow = x + (size_t)(rowBase + t) * DD;
        for (int d = 0; d < DD; ++d) {
            const float xd = xrow[d];
            const float* wr = Wn + d * NN;
            #pragma unroll
            for (int n = 0; n < NN; ++n) e[n] = fmaf(xd, wr[n], e[n]);
        }
        #pragma unroll
        for (int n = 0; n < NN; ++n) e[n] += sBn[n];
        EXPAND(e)
        best = 0; bv = L4a[0];
        #pragma unroll
        for (int l = 1; l < NL; ++l) if (L4a[l] > bv) { bv = L4a[l]; best = l; }
    }
    #undef EXPAND

    // ================= counting sort by leaf (3 barriers total) =================
    const int rank = atomicAdd(&sBins[best], 1);
    __syncthreads();                                   // barrier 2
    if (t == 0) {
        int s = 0, nt = 0;
        #pragma unroll
        for (int l = 0; l < NL; ++l) {
            sStarts[l] = s;
            const int cn = sBins[l];
            for (int m0 = s; m0 < s + cn; m0 += 16) {
                sTleaf[nt] = l; sTm0[nt] = m0; sTend[nt] = s + cn; ++nt;
            }
            s += cn;
        }
        sNT = nt;
    }
    __syncthreads();                                   // barrier 3
    sPerm[sStarts[best] + rank] = t;
    __syncthreads();                                   // barrier 4
    const int nT = sNT;

    // ================= phase 3: leaf GEMM, per-wave MFMA from global =================
    int tleaf[TPW], tm0[TPW], prow[TPW];
    #pragma unroll
    for (int i = 0; i < TPW; ++i) {
        const int tid = wv + i * 4;
        const bool vld = tid < nT;
        tleaf[i] = vld ? sTleaf[tid] : 0;
        tm0[i]   = vld ? sTm0[tid]   : 0;
        prow[i]  = sPerm[tm0[i] + lo16];
    }
    f32x4 accm[TPW];
    #pragma unroll
    for (int i = 0; i < TPW; ++i) accm[i] = (f32x4){0.f, 0.f, 0.f, 0.f};

    #pragma unroll 1
    for (int c = 0; c < 4; ++c) {
        #pragma unroll
        for (int i = 0; i < TPW; ++i) {
            if (wv + i * 4 < nT) {     // wave-uniform
                const float* ap = x + (size_t)(rowBase + prow[i]) * DD + c * 32 + grp * 8;
                const float4 a0 = *(const float4*)ap;
                const float4 a1 = *(const float4*)(ap + 4);
                float av[8];
                av[0]=a0.x; av[1]=a0.y; av[2]=a0.z; av[3]=a0.w;
                av[4]=a1.x; av[5]=a1.y; av[6]=a1.z; av[7]=a1.w;
                const short8v ah = pack8hi(av);
                const float* bp = Wl + (size_t)tleaf[i] * (DD * OC)
                                     + (size_t)(c * 32 + grp * 8) * OC + lo16;
                float bv2[8];
                #pragma unroll
                for (int j = 0; j < 8; ++j) bv2[j] = bp[j * 16];
                const short8v bh2 = pack8hi(bv2);
                accm[i] = __builtin_amdgcn_mfma_f32_16x16x32_bf16(ah, bh2, accm[i], 0, 0, 0);
            }
        }
    }

    // ---- epilogue: bias + squash + predicated scattered store ----
    #pragma unroll
    for (int i = 0; i < TPW; ++i) {
        const int tid = wv + i * 4;
        if (tid < nT) {
            const float bias = sBl[tleaf[i] * OC + lo16];
            const int tend = sTend[tid];
            #pragma unroll
            for (int j = 0; j < 4; ++j) {
                const int sl = tm0[i] + grp * 4 + j;
                if (sl < tend) {
                    const int r = sPerm[sl];
                    const size_t grow = (size_t)rowBase + r;
                    const float v = accm[i][j] + bias;
                    if (lo16 < 8) {
                        out[grow * 8 + lo16] = v;
                    } else {
                        // log_std = -1.5 + 3.5*tanh(v); tanh = 1 - 2/(e^{2v}+1)
                        out[(size_t)B * 8 + grow * 8 + (lo16 - 8)] =
                            -1.5f + 3.5f * (1.f - 2.f / (__expf(2.f * v) + 1.f));
                    }
                }
            }
        }
    }
}

extern "C" void kernel_launch(void* const* d_in, const int* in_sizes, int n_in,
                              void* d_out, int out_size, void* d_ws, size_t ws_size,
                              hipStream_t stream)
{
    const float* x  = (const float*)d_in[0];
    const float* Wn = (const float*)d_in[1];
    const float* bn = (const float*)d_in[2];
    const float* Wl = (const float*)d_in[3];
    const float* bl = (const float*)d_in[4];
    float* out = (float*)d_out;

    const int B = in_sizes[0] / DD;              // 262144
    const int blocks = (B + BLK - 1) / BLK;      // 1024

    hipLaunchKernelGGL(dts_fused9, dim3(blocks), dim3(BLK), 0, stream,
                       x, Wn, bn, Wl, bl, out, B);
}